// Round 19
// baseline (323.020 us; speedup 1.0000x reference)
//
#include <hip/hip_runtime.h>
#include <hip/hip_fp16.h>

// GCNNodeEdge: 4x GCNConv (+self-loops, sym-norm) + BN(train) + ReLU, lid branch, mask, sum.
// N=50000, E=800000.
// R19: (1) deg-atomics split across TWO dc replicas (edge-block parity) -> halves same-address
//      contention; slot offset reconstructed in fill via cnt0.  (2) 128-wide gathers split into
//      two sequential 64-column passes -> per-pass h-slice 3.2MB fits per-XCD L2.

static constexpr int NN = 50000;
static constexpr int EE = 800000;
static constexpr float EPS = 1e-5f;
static constexpr int SB = 128;  // col_stats blocks

typedef __attribute__((ext_vector_type(8))) short short8;
typedef __attribute__((ext_vector_type(4))) float f32x4;

// ---------- bf16 helpers ----------
__device__ __forceinline__ float bf2f_lo(unsigned w) { return __uint_as_float(w << 16); }
__device__ __forceinline__ float bf2f_hi(unsigned w) { return __uint_as_float(w & 0xFFFF0000u); }
__device__ __forceinline__ unsigned short f2bf(float f) {
    unsigned u = __float_as_uint(f);
    u = u + 0x7FFFu + ((u >> 16) & 1u);
    return (unsigned short)(u >> 16);
}
__device__ __forceinline__ unsigned pack2(float a, float b) {
    return (unsigned)f2bf(a) | ((unsigned)f2bf(b) << 16);
}

// ---------- fp8 e5m2 helpers ----------
__device__ __forceinline__ unsigned char f2e5(float f) {
    unsigned short h = __half_as_ushort(__float2half(f));
    unsigned v = (unsigned)h + 0x7Fu + ((h >> 8) & 1u);
    return (unsigned char)(v >> 8);
}
__device__ __forceinline__ void dec4(unsigned w, float* o) {
    o[0] = __half2float(__ushort_as_half((unsigned short)((w << 8) & 0xFF00u)));
    o[1] = __half2float(__ushort_as_half((unsigned short)(w & 0xFF00u)));
    o[2] = __half2float(__ushort_as_half((unsigned short)((w >> 8) & 0xFF00u)));
    o[3] = __half2float(__ushort_as_half((unsigned short)((w >> 16) & 0xFF00u)));
}
__device__ __forceinline__ unsigned packe4(float a, float b, float c, float d) {
    return (unsigned)f2e5(a) | ((unsigned)f2e5(b) << 8) |
           ((unsigned)f2e5(c) << 16) | ((unsigned)f2e5(d) << 24);
}

// ---------- mega-fused preprocess, INTERLEAVED roles; dual-dc atomics ----------
__global__ __launch_bounds__(256) void preprocess(
    const int* __restrict__ dst, const float* __restrict__ ew,
    unsigned long long* __restrict__ dc0, unsigned long long* __restrict__ dc1,
    unsigned short* __restrict__ slot, int E,
    const float* __restrict__ x_in, unsigned char* __restrict__ x8, int n,
    const float* __restrict__ lid_ts, unsigned short* __restrict__ lidb,
    const float* __restrict__ W1, unsigned short* __restrict__ W1t,
    const float* __restrict__ Wlid, unsigned short* __restrict__ Wlt,
    const float* __restrict__ W2, unsigned short* __restrict__ W2t,
    const float* __restrict__ W3, unsigned short* __restrict__ W3t)
{
    const int tid = threadIdx.x;
    const int period = blockIdx.x >> 4;
    const int off = blockIdx.x & 15;

    if (off < 5) {
        const int bd = period * 5 + off;
        const int e = bd * 256 + tid;
        if (e < E) {
            unsigned long long* dc = (bd & 1) ? dc1 : dc0;
            const unsigned long long v =
                (1ULL << 40) | (unsigned long long)(unsigned)(ew[e] * 67108864.0f + 0.5f);
            const unsigned long long old = atomicAdd(&dc[dst[e]], v);
            slot[e] = (unsigned short)(old >> 40);
        }
        return;
    }

    int b = period * 11 + (off - 5);
    const int B_x = (n * 8 + 255) / 256;
    if (b < B_x) {
        const long base = ((long)b * 256 + tid) * 8;
        if (base < (long)n * 64) {
            const float4 a = *reinterpret_cast<const float4*>(x_in + base);
            const float4 c = *reinterpret_cast<const float4*>(x_in + base + 4);
            uint2 w;
            w.x = packe4(a.x, a.y, a.z, a.w);
            w.y = packe4(c.x, c.y, c.z, c.w);
            *reinterpret_cast<uint2*>(x8 + base) = w;
        }
        return;
    }
    b -= B_x;
    const int B_lid = (n * 28 + 255) / 256;
    if (b < B_lid) {
        const int idx = b * 256 + tid;
        if (idx < n * 28) {
            const int row = idx / 28;
            const int c = (idx % 28) * 8;
            unsigned short vals[8];
#pragma unroll
            for (int j = 0; j < 8; ++j) {
                const int k = c + j;
                vals[j] = (k < 195) ? f2bf(lid_ts[(size_t)row * 195 + k]) : (unsigned short)0;
            }
            *reinterpret_cast<uint4*>(lidb + (size_t)row * 224 + c) = *reinterpret_cast<uint4*>(vals);
        }
        return;
    }
    b -= B_lid;
    const float* Wsrc;
    unsigned short* Wdst;
    int K, KR, M;
    if (b < 32)        { Wsrc = W1;   Wdst = W1t; K = 64;  KR = 64;  M = 128; }
    else if (b < 144)  { b -= 32;  Wsrc = Wlid; Wdst = Wlt; K = 224; KR = 195; M = 128; }
    else if (b < 272)  { b -= 144; Wsrc = W2;   Wdst = W2t; K = 128; KR = 128; M = 256; }
    else if (b < 400)  { b -= 272; Wsrc = W3;   Wdst = W3t; K = 256; KR = 256; M = 128; }
    else return;
    const int idx = b * 256 + tid;
    if (idx < M * K) {
        const int m = idx / K;
        const int k = idx % K;
        Wdst[idx] = (k < KR) ? f2bf(Wsrc[(size_t)k * M + m]) : (unsigned short)0;
    }
}

// ---------- CSR build (counts = dc0 + dc1) ----------
__global__ void scan_block(const unsigned long long* __restrict__ dc0,
                           const unsigned long long* __restrict__ dc1,
                           int* __restrict__ incl, int* __restrict__ bsum, int n) {
    __shared__ int sm[256];
    int i = blockIdx.x * 256 + threadIdx.x;
    int v = (i < n) ? (int)((dc0[i] >> 40) + (dc1[i] >> 40)) : 0;
    sm[threadIdx.x] = v;
    __syncthreads();
    for (int off = 1; off < 256; off <<= 1) {
        int t = (threadIdx.x >= off) ? sm[threadIdx.x - off] : 0;
        __syncthreads();
        sm[threadIdx.x] += t;
        __syncthreads();
    }
    if (i < n) incl[i] = sm[threadIdx.x];
    if (threadIdx.x == 255) bsum[blockIdx.x] = sm[255];
}

__global__ void scan_sums(int* __restrict__ bsum, int nb) {
    __shared__ int sm[256];
    int v = (threadIdx.x < nb) ? bsum[threadIdx.x] : 0;
    sm[threadIdx.x] = v;
    __syncthreads();
    for (int off = 1; off < 256; off <<= 1) {
        int t = (threadIdx.x >= off) ? sm[threadIdx.x - off] : 0;
        __syncthreads();
        sm[threadIdx.x] += t;
        __syncthreads();
    }
    if (threadIdx.x < nb) bsum[threadIdx.x] = sm[threadIdx.x];
}

__global__ void make_row(const unsigned long long* __restrict__ dc0,
                         const unsigned long long* __restrict__ dc1,
                         const int* __restrict__ incl, const int* __restrict__ bsum,
                         int* __restrict__ row, float* __restrict__ dinv, int n, int E) {
    int i = blockIdx.x * 256 + threadIdx.x;
    if (i < n) {
        int b = i >> 8;
        int base = b > 0 ? bsum[b - 1] : 0;
        const unsigned long long v0 = dc0[i];
        const unsigned long long v1 = dc1[i];
        const int c = (int)((v0 >> 40) + (v1 >> 40));
        row[i] = base + incl[i] - c;
        const float qsum = (float)((v0 & 0xFFFFFFFFFFULL) + (v1 & 0xFFFFFFFFFFULL));
        dinv[i] = rsqrtf(1.0f + qsum * (1.0f / 67108864.0f));
    } else if (i == n) {
        row[n] = E;
    }
}

// ---------- shared MFMA GEMM body ----------
template<int K, int KR, int M, int XMODE, bool OB, bool STATS>
__device__ __forceinline__ void mfma_body(
    int bx, int by,
    const unsigned short* __restrict__ Xb, const unsigned short* __restrict__ Wt,
    const float* __restrict__ bias,
    const float* __restrict__ mr, const float* __restrict__ g, const float* __restrict__ be,
    void* __restrict__ Hv, float* __restrict__ parts, int n,
    unsigned short* A_lds, unsigned short* B_lds)
{
    const int tid = threadIdx.x;
    const int r0 = bx * 64;
    const int c0 = by * 64;
    const int srow = tid >> 2;
    const int skc  = tid & 3;
    const int gr   = r0 + srow;
    const int lane = tid & 63;
    const int wv_  = tid >> 6;
    const int arow = wv_ * 16 + (lane & 15);
    const int koff = (lane >> 4) * 8;

    f32x4 acc[4];
#pragma unroll
    for (int ct = 0; ct < 4; ++ct) acc[ct] = (f32x4){0.f, 0.f, 0.f, 0.f};

    for (int kt = 0; kt < K / 32; ++kt) {
        const int k0 = kt * 32;
        const int kb = k0 + skc * 8;
        unsigned short vals[8];
        if constexpr (XMODE == 0) {
            if (gr < n) {
                *reinterpret_cast<uint4*>(vals) =
                    *reinterpret_cast<const uint4*>(Xb + (size_t)gr * KR + kb);
            } else {
#pragma unroll
                for (int j = 0; j < 8; ++j) vals[j] = 0;
            }
        } else {
            if (gr < n) {
                const uint4 wq = *reinterpret_cast<const uint4*>(Xb + (size_t)gr * K + kb);
                const unsigned ws[4] = {wq.x, wq.y, wq.z, wq.w};
#pragma unroll
                for (int j = 0; j < 4; ++j) {
                    const int c = kb + 2 * j;
                    float a = bf2f_lo(ws[j]);
                    float bq = bf2f_hi(ws[j]);
                    float t0 = (a - mr[c]) * mr[K + c] * g[c] + be[c];
                    float t1 = (bq - mr[c + 1]) * mr[K + c + 1] * g[c + 1] + be[c + 1];
                    vals[2 * j]     = f2bf(t0 > 0.f ? t0 : 0.f);
                    vals[2 * j + 1] = f2bf(t1 > 0.f ? t1 : 0.f);
                }
            } else {
#pragma unroll
                for (int j = 0; j < 8; ++j) vals[j] = 0;
            }
        }
        *reinterpret_cast<uint4*>(&A_lds[srow * 40 + skc * 8]) = *reinterpret_cast<uint4*>(vals);
        *reinterpret_cast<uint4*>(&B_lds[srow * 40 + skc * 8]) =
            *reinterpret_cast<const uint4*>(Wt + (size_t)(c0 + srow) * K + k0 + skc * 8);
        __syncthreads();

        const short8 af = *reinterpret_cast<const short8*>(&A_lds[arow * 40 + koff]);
#pragma unroll
        for (int ct = 0; ct < 4; ++ct) {
            const short8 bf = *reinterpret_cast<const short8*>(&B_lds[(ct * 16 + (lane & 15)) * 40 + koff]);
            acc[ct] = __builtin_amdgcn_mfma_f32_16x16x32_bf16(af, bf, acc[ct], 0, 0, 0);
        }
        __syncthreads();
    }

    const int colb = c0 + (lane & 15);
    const int rowb = r0 + wv_ * 16 + (lane >> 4) * 4;
    float cs[4] = {0.f, 0.f, 0.f, 0.f}, cq[4] = {0.f, 0.f, 0.f, 0.f};
#pragma unroll
    for (int ct = 0; ct < 4; ++ct) {
        const int gcol = colb + ct * 16;
        const float bv = bias ? bias[gcol] : 0.f;
#pragma unroll
        for (int r = 0; r < 4; ++r) {
            const int grow = rowb + r;
            if (grow < n) {
                const float val = acc[ct][r] + bv;
                if constexpr (OB) ((unsigned char*)Hv)[(size_t)grow * M + gcol] = f2e5(val);
                else ((unsigned short*)Hv)[(size_t)grow * M + gcol] = f2bf(val);
                if constexpr (STATS) { cs[ct] += val; cq[ct] += val * val; }
            }
        }
    }

    if constexpr (STATS) {
#pragma unroll
        for (int ct = 0; ct < 4; ++ct) {
            cs[ct] += __shfl_xor(cs[ct], 16);
            cs[ct] += __shfl_xor(cs[ct], 32);
            cq[ct] += __shfl_xor(cq[ct], 16);
            cq[ct] += __shfl_xor(cq[ct], 32);
        }
        float* scr = reinterpret_cast<float*>(A_lds);
        if ((lane & 15) == lane) {
#pragma unroll
            for (int ct = 0; ct < 4; ++ct) {
                scr[(wv_ * 4 + ct) * 16 + lane] = cs[ct];
                scr[256 + (wv_ * 4 + ct) * 16 + lane] = cq[ct];
            }
        }
        __syncthreads();
        if (tid < 64) {
            const int ct = tid >> 4;
            const int col = tid & 15;
            float s = 0.f, q = 0.f;
#pragma unroll
            for (int w2 = 0; w2 < 4; ++w2) {
                s += scr[(w2 * 4 + ct) * 16 + col];
                q += scr[256 + (w2 * 4 + ct) * 16 + col];
            }
            const int gcol = c0 + ct * 16 + col;
            parts[(size_t)bx * (2 * M) + gcol] = s;
            parts[(size_t)bx * (2 * M) + M + gcol] = q;
        }
    }
}

template<int K, int KR, int M, int XMODE, bool OB, bool STATS>
__global__ __launch_bounds__(256) void mfma_gemm(
    const unsigned short* __restrict__ Xb, const unsigned short* __restrict__ Wt,
    const float* __restrict__ bias,
    const float* __restrict__ mr, const float* __restrict__ g, const float* __restrict__ be,
    void* __restrict__ Hv, float* __restrict__ parts, int n)
{
    __shared__ __attribute__((aligned(16))) unsigned short A_lds[64 * 40];
    __shared__ __attribute__((aligned(16))) unsigned short B_lds[64 * 40];
    mfma_body<K, KR, M, XMODE, OB, STATS>(blockIdx.x, blockIdx.y, Xb, Wt, bias, mr, g, be,
                                          Hv, parts, n, A_lds, B_lds);
}

// ---------- fill_csr interleaved with lid GEMM (period 3: 2 fill + 1 gemm) ----------
__global__ __launch_bounds__(256) void fill_lid(
    const int* __restrict__ src, const int* __restrict__ dst,
    const float* __restrict__ ew, const float* __restrict__ dinv,
    const int* __restrict__ row, const unsigned short* __restrict__ slot,
    const unsigned long long* __restrict__ dc0,
    unsigned* __restrict__ recs, int E,
    const unsigned short* __restrict__ lidb, const unsigned short* __restrict__ Wlt,
    const float* __restrict__ blid, unsigned short* __restrict__ Ch, int n)
{
    __shared__ __attribute__((aligned(16))) unsigned short A_lds[64 * 40];
    __shared__ __attribute__((aligned(16))) unsigned short B_lds[64 * 40];
    const int period = blockIdx.x / 3;
    const int off = blockIdx.x % 3;
    if (off < 2) {
        const int e = (period * 2 + off) * 256 + threadIdx.x;
        if (e < E) {
            const int s = src[e], d = dst[e];
            const float nm = dinv[s] * ew[e] * dinv[d];
            const unsigned q = (unsigned)fminf(nm * 32767.0f + 0.5f, 32767.0f);
            const int rep = (e >> 8) & 1;
            const int extra = rep ? (int)(dc0[d] >> 40) : 0;
            const int p = row[d] + (int)slot[e] + extra;
            recs[p] = ((unsigned)s << 15) | q;
        }
        return;
    }
    const int bx = period >> 1;
    const int by = period & 1;
    if (bx >= 782) return;
    mfma_body<224, 224, 128, 0, false, false>(bx, by, lidb, Wlt, blid, nullptr, nullptr, nullptr,
                                              Ch, nullptr, n, A_lds, B_lds);
}

// ---------- row-per-thread GEMM (layer 4: K=128, M=24), bf16 in, fp8 out ----------
template<int K, int M, bool XFORM>
__global__ __launch_bounds__(256) void gemm_rowwise(
    const unsigned short* __restrict__ X, const float* __restrict__ W,
    const float* __restrict__ mr, const float* __restrict__ g,
    const float* __restrict__ be, unsigned char* __restrict__ Hb, int n)
{
    __shared__ float Ws[K * M];
    __shared__ float sc[K], sh[K];
    for (int i = threadIdx.x; i < K * M; i += 256) Ws[i] = W[i];
    if (XFORM) {
        for (int i = threadIdx.x; i < K; i += 256) {
            float s = mr[K + i] * g[i];
            sc[i] = s;
            sh[i] = be[i] - mr[i] * s;
        }
    }
    __syncthreads();

    const int row = blockIdx.x * 256 + threadIdx.x;
    if (row >= n) return;

    float acc[M];
#pragma unroll
    for (int c = 0; c < M; ++c) acc[c] = 0.f;

#pragma unroll 2
    for (int kq = 0; kq < K / 8; ++kq) {
        const uint4 wv = *reinterpret_cast<const uint4*>(X + (size_t)row * K + kq * 8);
        const unsigned ws[4] = {wv.x, wv.y, wv.z, wv.w};
#pragma unroll
        for (int j = 0; j < 4; ++j) {
            const int k = kq * 8 + 2 * j;
            float x0 = bf2f_lo(ws[j]);
            float x1 = bf2f_hi(ws[j]);
            if (XFORM) {
                x0 = x0 * sc[k] + sh[k];       x0 = x0 > 0.f ? x0 : 0.f;
                x1 = x1 * sc[k + 1] + sh[k + 1]; x1 = x1 > 0.f ? x1 : 0.f;
            }
#pragma unroll
            for (int c4 = 0; c4 < M / 4; ++c4) {
                const float4 w0 = *reinterpret_cast<const float4*>(&Ws[k * M + c4 * 4]);
                const float4 w1 = *reinterpret_cast<const float4*>(&Ws[(k + 1) * M + c4 * 4]);
                acc[c4 * 4 + 0] += x0 * w0.x + x1 * w1.x;
                acc[c4 * 4 + 1] += x0 * w0.y + x1 * w1.y;
                acc[c4 * 4 + 2] += x0 * w0.z + x1 * w1.z;
                acc[c4 * 4 + 3] += x0 * w0.w + x1 * w1.w;
            }
        }
    }
#pragma unroll
    for (int q = 0; q < M / 8; ++q) {
        uint2 w;
        w.x = packe4(acc[q * 8 + 0], acc[q * 8 + 1], acc[q * 8 + 2], acc[q * 8 + 3]);
        w.y = packe4(acc[q * 8 + 4], acc[q * 8 + 5], acc[q * 8 + 6], acc[q * 8 + 7]);
        *reinterpret_cast<uint2*>(Hb + (size_t)row * M + q * 8) = w;
    }
}

// ---------- CSR gather (fp8 in, fp32 accum, bf16 out), NO LDS ----------
// MW = columns processed this pass; ld = row stride; fbase = first column.
template<int MW>
__global__ __launch_bounds__(256) void gather_e5(
    const unsigned char* __restrict__ h, const int* __restrict__ row,
    const unsigned* __restrict__ recs,
    const float* __restrict__ dinv, const float* __restrict__ bias,
    unsigned short* __restrict__ agg, int ld, int fbase, int n)
{
    constexpr int PF = MW / 8;
    const int idx = blockIdx.x * 256 + threadIdx.x;
    const int i = idx / PF;
    if (i >= n) return;
    const int f = fbase + (idx % PF) * 8;

    float acc[8];
    {
        const uint2 w = *reinterpret_cast<const uint2*>(h + (size_t)i * ld + f);
        dec4(w.x, acc);
        dec4(w.y, acc + 4);
    }
    const float di = dinv[i];
    const float d2 = di * di;
#pragma unroll
    for (int j = 0; j < 8; ++j) acc[j] *= d2;
    if (bias) {
#pragma unroll
        for (int j = 0; j < 8; ++j) acc[j] += bias[f + j];
    }

    const int p0 = row[i], p1 = row[i + 1];
    int p = p0;
    for (; p + 2 <= p1; p += 2) {
        const unsigned r0 = recs[p], r1 = recs[p + 1];
        const int s0 = (int)(r0 >> 15), s1 = (int)(r1 >> 15);
        const float nw0 = (float)(r0 & 0x7FFFu) * (1.0f / 32767.0f);
        const float nw1 = (float)(r1 & 0x7FFFu) * (1.0f / 32767.0f);
        const uint2 a = *reinterpret_cast<const uint2*>(h + (size_t)s0 * ld + f);
        const uint2 b = *reinterpret_cast<const uint2*>(h + (size_t)s1 * ld + f);
        float tv[4];
        dec4(a.x, tv);
        acc[0] += nw0 * tv[0]; acc[1] += nw0 * tv[1]; acc[2] += nw0 * tv[2]; acc[3] += nw0 * tv[3];
        dec4(a.y, tv);
        acc[4] += nw0 * tv[0]; acc[5] += nw0 * tv[1]; acc[6] += nw0 * tv[2]; acc[7] += nw0 * tv[3];
        dec4(b.x, tv);
        acc[0] += nw1 * tv[0]; acc[1] += nw1 * tv[1]; acc[2] += nw1 * tv[2]; acc[3] += nw1 * tv[3];
        dec4(b.y, tv);
        acc[4] += nw1 * tv[0]; acc[5] += nw1 * tv[1]; acc[6] += nw1 * tv[2]; acc[7] += nw1 * tv[3];
    }
    if (p < p1) {
        const unsigned r0 = recs[p];
        const int s0 = (int)(r0 >> 15);
        const float nw0 = (float)(r0 & 0x7FFFu) * (1.0f / 32767.0f);
        const uint2 a = *reinterpret_cast<const uint2*>(h + (size_t)s0 * ld + f);
        float tv[4];
        dec4(a.x, tv);
        acc[0] += nw0 * tv[0]; acc[1] += nw0 * tv[1]; acc[2] += nw0 * tv[2]; acc[3] += nw0 * tv[3];
        dec4(a.y, tv);
        acc[4] += nw0 * tv[0]; acc[5] += nw0 * tv[1]; acc[6] += nw0 * tv[2]; acc[7] += nw0 * tv[3];
    }

    uint4 w;
    w.x = pack2(acc[0], acc[1]);
    w.y = pack2(acc[2], acc[3]);
    w.z = pack2(acc[4], acc[5]);
    w.w = pack2(acc[6], acc[7]);
    *reinterpret_cast<uint4*>(agg + (size_t)i * ld + f) = w;
}

// ---------- column stats (bf16 input): per-block partial slots, layout b*(2M) ----------
template<int M>
__global__ __launch_bounds__(256) void col_stats_b(const unsigned short* __restrict__ x,
                                                   float* __restrict__ parts, int n) {
    constexpr int PF = M / 8;
    constexpr int RT = 256 / PF;
    __shared__ float smS[256 * 8];
    __shared__ float smQ[256 * 8];
    const int t = threadIdx.x;
    const int f8 = t % PF;
    const int rg = t / PF;
    const bool active = rg < RT;

    float s[8] = {}, q[8] = {};
    if (active) {
        const int rowsPer = (n + gridDim.x - 1) / gridDim.x;
        const int r0 = blockIdx.x * rowsPer;
        const int r1 = min(r0 + rowsPer, n);
        for (int r = r0 + rg; r < r1; r += RT) {
            const uint4 w = *reinterpret_cast<const uint4*>(x + (size_t)r * M + f8 * 8);
            const unsigned ws[4] = {w.x, w.y, w.z, w.w};
#pragma unroll
            for (int j = 0; j < 4; ++j) {
                const float a = bf2f_lo(ws[j]);
                const float b = bf2f_hi(ws[j]);
                s[2 * j]     += a; q[2 * j]     += a * a;
                s[2 * j + 1] += b; q[2 * j + 1] += b * b;
            }
        }
    }
#pragma unroll
    for (int j = 0; j < 8; ++j) { smS[t * 8 + j] = s[j]; smQ[t * 8 + j] = q[j]; }
    __syncthreads();
    if (rg == 0) {
        for (int o = 1; o < RT; ++o) {
#pragma unroll
            for (int j = 0; j < 8; ++j) {
                s[j] += smS[(o * PF + f8) * 8 + j];
                q[j] += smQ[(o * PF + f8) * 8 + j];
            }
        }
        float* dstp = parts + (size_t)blockIdx.x * (2 * M) + f8 * 8;
#pragma unroll
        for (int j = 0; j < 8; ++j) { dstp[j] = s[j]; dstp[M + j] = q[j]; }
    }
}

// ---------- parallel stats finalize ----------
__global__ __launch_bounds__(256) void finalize_stats(
    const float* __restrict__ parts, float* __restrict__ mr,
    int stride, int nblk, int M, float n) {
    __shared__ float smS[256], smQ[256];
    const int t = threadIdx.x;
    const int col = blockIdx.x * 8 + (t & 7);
    const int rg = t >> 3;
    float s = 0.f, q = 0.f;
    if (col < M) {
        for (int b = rg; b < nblk; b += 32) {
            s += parts[(size_t)b * stride + col];
            q += parts[(size_t)b * stride + M + col];
        }
    }
    smS[t] = s;
    smQ[t] = q;
    __syncthreads();
    if (t < 8 && col < M) {
        for (int o = 1; o < 32; ++o) { s += smS[o * 8 + t]; q += smQ[o * 8 + t]; }
        const float mean = s / n;
        const float var = q / n - mean * mean;
        mr[col] = mean;
        mr[M + col] = rsqrtf(fmaxf(var, 0.f) + EPS);
    }
}

// layer1 epilogue: out_fp8 = mask ? 0 : relu(bn(xagg_bf16)) + relu(lid_bf16)   (M=128)
__global__ void bn_relu_lid_mask_e5(const unsigned short* __restrict__ xagg,
                                    const float* __restrict__ mr,
                                    const float* __restrict__ g, const float* __restrict__ be,
                                    const unsigned short* __restrict__ lid,
                                    const float* __restrict__ x_in,
                                    unsigned char* __restrict__ out, int n) {
    int idx = blockIdx.x * 256 + threadIdx.x;
    if (idx >= n * 16) return;
    const int i = idx >> 4;
    const int f = (idx & 15) * 8;
    const bool mask = x_in[(size_t)i * 64] == 0.f;
    const uint4 xv = *reinterpret_cast<const uint4*>(xagg + (size_t)i * 128 + f);
    const uint4 lv = *reinterpret_cast<const uint4*>(lid + (size_t)i * 128 + f);
    const unsigned xs[4] = {xv.x, xv.y, xv.z, xv.w};
    const unsigned ls[4] = {lv.x, lv.y, lv.z, lv.w};
    float o[8];
#pragma unroll
    for (int j = 0; j < 4; ++j) {
        const int c = f + 2 * j;
        float v0 = bf2f_lo(xs[j]), v1 = bf2f_hi(xs[j]);
        float l0 = bf2f_lo(ls[j]), l1 = bf2f_hi(ls[j]);
        float t0 = (v0 - mr[c]) * mr[128 + c] * g[c] + be[c];
        float t1 = (v1 - mr[c + 1]) * mr[128 + c + 1] * g[c + 1] + be[c + 1];
        t0 = (t0 > 0.f ? t0 : 0.f) + (l0 > 0.f ? l0 : 0.f);
        t1 = (t1 > 0.f ? t1 : 0.f) + (l1 > 0.f ? l1 : 0.f);
        o[2 * j]     = mask ? 0.f : t0;
        o[2 * j + 1] = mask ? 0.f : t1;
    }
    uint2 w;
    w.x = packe4(o[0], o[1], o[2], o[3]);
    w.y = packe4(o[4], o[5], o[6], o[7]);
    *reinterpret_cast<uint2*>(out + (size_t)i * 128 + f) = w;
}

// layer4 stage 1: out = relu(bn(x_bf16)) -> d_out fp32, block partials (no atomics)
template<int M>
__global__ __launch_bounds__(256) void bn_relu_partial_b(
    const unsigned short* __restrict__ x, const float* __restrict__ mr,
    const float* __restrict__ g, const float* __restrict__ be,
    float* __restrict__ out, float* __restrict__ partials, int total8) {
    float acc = 0.f;
    for (int c8 = blockIdx.x * 256 + threadIdx.x; c8 < total8; c8 += gridDim.x * 256) {
        const int base = c8 * 8;
        const uint4 w = *reinterpret_cast<const uint4*>(x + base);
        const unsigned ws[4] = {w.x, w.y, w.z, w.w};
        float o[8];
#pragma unroll
        for (int j = 0; j < 4; ++j) {
            const int f0 = (base + 2 * j) % M;
            const int f1 = (base + 2 * j + 1) % M;
            float v0 = bf2f_lo(ws[j]), v1 = bf2f_hi(ws[j]);
            v0 = (v0 - mr[f0]) * mr[M + f0] * g[f0] + be[f0];
            v1 = (v1 - mr[f1]) * mr[M + f1] * g[f1] + be[f1];
            o[2 * j]     = v0 > 0.f ? v0 : 0.f;
            o[2 * j + 1] = v1 > 0.f ? v1 : 0.f;
            acc += o[2 * j] + o[2 * j + 1];
        }
        *reinterpret_cast<float4*>(out + base)     = make_float4(o[0], o[1], o[2], o[3]);
        *reinterpret_cast<float4*>(out + base + 4) = make_float4(o[4], o[5], o[6], o[7]);
    }
    __shared__ float red[256];
    red[threadIdx.x] = acc;
    __syncthreads();
    for (int s = 128; s > 0; s >>= 1) {
        if (threadIdx.x < s) red[threadIdx.x] += red[threadIdx.x + s];
        __syncthreads();
    }
    if (threadIdx.x == 0) partials[blockIdx.x] = red[0];
}

__global__ void final_sum(const float* __restrict__ partials, int nb, float* __restrict__ sumout) {
    float v = 0.f;
    for (int i = threadIdx.x; i < nb; i += 256) v += partials[i];
    __shared__ float red[256];
    red[threadIdx.x] = v;
    __syncthreads();
    for (int s = 128; s > 0; s >>= 1) {
        if (threadIdx.x < s) red[threadIdx.x] += red[threadIdx.x + s];
        __syncthreads();
    }
    if (threadIdx.x == 0) *sumout = red[0];
}

// ---------------------------------------------------------------
extern "C" void kernel_launch(void* const* d_in, const int* in_sizes, int n_in,
                              void* d_out, int out_size, void* d_ws, size_t ws_size,
                              hipStream_t stream) {
    const float* x_in   = (const float*)d_in[0];
    const int*   eidx   = (const int*)d_in[1];
    const float* ew     = (const float*)d_in[2];
    const float* lid_ts = (const float*)d_in[3];
    const float* W1   = (const float*)d_in[4];
    const float* b1   = (const float*)d_in[5];
    const float* Wlid = (const float*)d_in[6];
    const float* blid = (const float*)d_in[7];
    const float* W2   = (const float*)d_in[8];
    const float* b2   = (const float*)d_in[9];
    const float* W3   = (const float*)d_in[10];
    const float* b3   = (const float*)d_in[11];
    const float* W4   = (const float*)d_in[12];
    const float* b4   = (const float*)d_in[13];
    const float* g1   = (const float*)d_in[14];
    const float* be1  = (const float*)d_in[15];
    const float* g2   = (const float*)d_in[16];
    const float* be2  = (const float*)d_in[17];
    const float* g3   = (const float*)d_in[18];
    const float* be3  = (const float*)d_in[19];
    const float* g4   = (const float*)d_in[20];
    const float* be4  = (const float*)d_in[21];

    const int n = in_sizes[0] / 64;   // 50000
    const int E = in_sizes[2];        // 800000
    const int* src = eidx;
    const int* dst = eidx + E;

    // workspace layout
    float* dinv  = (float*)d_ws;              // NN
    float* parts = dinv + NN;                 // 800000
    float* mr    = parts + 800000;            // 512
    float* partials = mr + 512;               // 512
    unsigned long long* dc0 = (unsigned long long*)(partials + 512);  // NN ull
    unsigned long long* dc1 = dc0 + NN;                               // NN ull
    unsigned short* Bh  = (unsigned short*)(dc1 + NN);   // NN*256 bf16
    unsigned short* Ch  = Bh + (size_t)NN * 256;         // NN*128 bf16
    unsigned short* Gh  = Ch + (size_t)NN * 128;         // NN*128 bf16
    unsigned short* Gb  = Gh + (size_t)NN * 128;         // NN*128 bf16
    unsigned short* lidb = Gb + (size_t)NN * 128;        // NN*224 bf16
    unsigned short* W1t = lidb + (size_t)NN * 224;       // 128*64
    unsigned short* Wlt = W1t + 128 * 64;                // 128*224
    unsigned short* W2t = Wlt + 128 * 224;               // 256*128
    unsigned short* W3t = W2t + 256 * 128;               // 128*256
    unsigned char* x8   = (unsigned char*)(W3t + 128 * 256);  // NN*64 fp8
    unsigned char* Cb8  = x8 + (size_t)NN * 64;          // NN*128 fp8
    unsigned char* Bb8  = Cb8 + (size_t)NN * 128;        // NN*24 fp8
    int* incl    = (int*)((((size_t)(Bb8 + (size_t)NN * 24) + 3) / 4) * 4);  // NN
    int* bsum    = incl + NN;                 // 256
    int* row     = bsum + 256;                // NN+2
    unsigned short* slot = (unsigned short*)(row + NN + 2);  // EE ushort
    unsigned* recs = (unsigned*)(slot + EE);  // EE u32

    float* outx = (float*)d_out;              // n*24
    float* outsum = outx + (size_t)n * 24;    // 1

    hipMemsetAsync(dc0, 0, (size_t)2 * NN * sizeof(unsigned long long), stream);

    // ---- interleaved preprocess (dual-dc atomics) ----
    const int B_deg = (E + 255) / 256;            // 3125
    const int B_x   = (n * 8 + 255) / 256;        // 1563
    const int B_lid = (n * 28 + 255) / 256;       // 5469
    const int B_w   = 400;
    const int B_other = B_x + B_lid + B_w;
    const int periods = max((B_deg + 4) / 5, (B_other + 10) / 11);
    preprocess<<<periods * 16, 256, 0, stream>>>(
        dst, ew, dc0, dc1, slot, E, x_in, x8, n, lid_ts, lidb,
        W1, W1t, Wlid, Wlt, W2, W2t, W3, W3t);

    // ---- CSR scan ----
    const int nb = (n + 255) / 256;
    scan_block<<<nb, 256, 0, stream>>>(dc0, dc1, incl, bsum, n);
    scan_sums<<<1, 256, 0, stream>>>(bsum, nb);
    make_row<<<(n + 1 + 255) / 256, 256, 0, stream>>>(dc0, dc1, incl, bsum, row, dinv, n, E);

    // ---- fill interleaved with lid GEMM ----
    fill_lid<<<1564 * 3, 256, 0, stream>>>(src, dst, ew, dinv, row, slot, dc0, recs, E,
                                           lidb, Wlt, blid, Ch, n);

    const int gm64 = (n + 63) / 64;   // 782
    const int gHalf = ((size_t)n * 8 + 255) / 256;  // 1563 blocks per 64-col pass

    // ---- layer 1: gather(64) -> MFMA(stats) -> finalize -> epilogue ----
    gather_e5<64><<<gHalf, 256, 0, stream>>>(x8, row, recs, dinv, nullptr, Gb, 64, 0, n);
    mfma_gemm<64, 64, 128, 0, false, true><<<dim3(gm64, 2), 256, 0, stream>>>(Gb, W1t, b1, nullptr, nullptr, nullptr, Bh, parts, n);
    finalize_stats<<<16, 256, 0, stream>>>(parts, mr, 256, gm64, 128, (float)n);
    bn_relu_lid_mask_e5<<<((size_t)n * 16 + 255) / 256, 256, 0, stream>>>(Bh, mr, g1, be1, Ch, x_in, Cb8, n);

    // ---- layer 2: gather(128 = 2x64-col passes) -> MFMA(stats) -> finalize ----
    gather_e5<64><<<gHalf, 256, 0, stream>>>(Cb8, row, recs, dinv, nullptr, Gb, 128, 0, n);
    gather_e5<64><<<gHalf, 256, 0, stream>>>(Cb8, row, recs, dinv, nullptr, Gb, 128, 64, n);
    mfma_gemm<128, 128, 256, 0, false, true><<<dim3(gm64, 4), 256, 0, stream>>>(Gb, W2t, b2, nullptr, nullptr, nullptr, Bh, parts, n);
    finalize_stats<<<32, 256, 0, stream>>>(parts, mr, 512, gm64, 256, (float)n);

    // ---- layer 3: MFMA(BN2 fused, fp8 out) -> gather(2 passes) -> col_stats -> finalize ----
    mfma_gemm<256, 256, 128, 1, true, false><<<dim3(gm64, 2), 256, 0, stream>>>(Bh, W3t, nullptr, mr, g2, be2, Cb8, nullptr, n);
    gather_e5<64><<<gHalf, 256, 0, stream>>>(Cb8, row, recs, dinv, b3, Gh, 128, 0, n);
    gather_e5<64><<<gHalf, 256, 0, stream>>>(Cb8, row, recs, dinv, b3, Gh, 128, 64, n);
    col_stats_b<128><<<SB, 256, 0, stream>>>(Gh, parts, n);
    finalize_stats<<<16, 256, 0, stream>>>(parts, mr, 256, SB, 128, (float)n);

    // ---- layer 4: rowwise GEMM(BN3 fused, fp8 out) -> gather -> col_stats -> finalize -> epilogue+sum ----
    gemm_rowwise<128, 24, true><<<(n + 255) / 256, 256, 0, stream>>>(Gh, W4, mr, g3, be3, Bb8, n);
    gather_e5<24><<<((size_t)n * 3 + 255) / 256, 256, 0, stream>>>(Bb8, row, recs, dinv, b4, Ch, 24, 0, n);
    col_stats_b<24><<<SB, 256, 0, stream>>>(Ch, parts, n);
    finalize_stats<<<3, 256, 0, stream>>>(parts, mr, 48, SB, 24, (float)n);
    bn_relu_partial_b<24><<<240, 256, 0, stream>>>(Ch, mr, g4, be4, outx, partials, n * 24 / 8);
    final_sum<<<1, 256, 0, stream>>>(partials, 240, outsum);
}

// Round 20
// 305.345 us; speedup vs baseline: 1.0579x; 1.0579x over previous
//
#include <hip/hip_runtime.h>
#include <hip/hip_fp16.h>

// GCNNodeEdge: 4x GCNConv (+self-loops, sym-norm) + BN(train) + ReLU, lid branch, mask, sum.
// N=50000, E=800000.
// R20: exact revert to R18 (best: 308us). R19's dual-dc (atomics not contention-bound) and
//      gather column-split (fp8 128B rows -> same cache lines touched) both refuted by counters.

static constexpr int NN = 50000;
static constexpr int EE = 800000;
static constexpr float EPS = 1e-5f;
static constexpr int SB = 128;  // col_stats blocks

typedef __attribute__((ext_vector_type(8))) short short8;
typedef __attribute__((ext_vector_type(4))) float f32x4;

// ---------- bf16 helpers ----------
__device__ __forceinline__ float bf2f_lo(unsigned w) { return __uint_as_float(w << 16); }
__device__ __forceinline__ float bf2f_hi(unsigned w) { return __uint_as_float(w & 0xFFFF0000u); }
__device__ __forceinline__ unsigned short f2bf(float f) {
    unsigned u = __float_as_uint(f);
    u = u + 0x7FFFu + ((u >> 16) & 1u);
    return (unsigned short)(u >> 16);
}
__device__ __forceinline__ unsigned pack2(float a, float b) {
    return (unsigned)f2bf(a) | ((unsigned)f2bf(b) << 16);
}

// ---------- fp8 e5m2 helpers ----------
__device__ __forceinline__ unsigned char f2e5(float f) {
    unsigned short h = __half_as_ushort(__float2half(f));
    unsigned v = (unsigned)h + 0x7Fu + ((h >> 8) & 1u);
    return (unsigned char)(v >> 8);
}
__device__ __forceinline__ void dec4(unsigned w, float* o) {
    o[0] = __half2float(__ushort_as_half((unsigned short)((w << 8) & 0xFF00u)));
    o[1] = __half2float(__ushort_as_half((unsigned short)(w & 0xFF00u)));
    o[2] = __half2float(__ushort_as_half((unsigned short)((w >> 8) & 0xFF00u)));
    o[3] = __half2float(__ushort_as_half((unsigned short)((w >> 16) & 0xFF00u)));
}
__device__ __forceinline__ unsigned packe4(float a, float b, float c, float d) {
    return (unsigned)f2e5(a) | ((unsigned)f2e5(b) << 8) |
           ((unsigned)f2e5(c) << 16) | ((unsigned)f2e5(d) << 24);
}

// ---------- mega-fused preprocess, INTERLEAVED roles ----------
__global__ __launch_bounds__(256) void preprocess(
    const int* __restrict__ dst, const float* __restrict__ ew,
    unsigned long long* __restrict__ dc, unsigned short* __restrict__ slot, int E,
    const float* __restrict__ x_in, unsigned char* __restrict__ x8, int n,
    const float* __restrict__ lid_ts, unsigned short* __restrict__ lidb,
    const float* __restrict__ W1, unsigned short* __restrict__ W1t,
    const float* __restrict__ Wlid, unsigned short* __restrict__ Wlt,
    const float* __restrict__ W2, unsigned short* __restrict__ W2t,
    const float* __restrict__ W3, unsigned short* __restrict__ W3t)
{
    const int tid = threadIdx.x;
    const int period = blockIdx.x >> 4;
    const int off = blockIdx.x & 15;

    if (off < 5) {
        const int bd = period * 5 + off;
        const int e = bd * 256 + tid;
        if (e < E) {
            const unsigned long long v =
                (1ULL << 40) | (unsigned long long)(unsigned)(ew[e] * 67108864.0f + 0.5f);
            const unsigned long long old = atomicAdd(&dc[dst[e]], v);
            slot[e] = (unsigned short)(old >> 40);
        }
        return;
    }

    int b = period * 11 + (off - 5);
    const int B_x = (n * 8 + 255) / 256;
    if (b < B_x) {
        const long base = ((long)b * 256 + tid) * 8;
        if (base < (long)n * 64) {
            const float4 a = *reinterpret_cast<const float4*>(x_in + base);
            const float4 c = *reinterpret_cast<const float4*>(x_in + base + 4);
            uint2 w;
            w.x = packe4(a.x, a.y, a.z, a.w);
            w.y = packe4(c.x, c.y, c.z, c.w);
            *reinterpret_cast<uint2*>(x8 + base) = w;
        }
        return;
    }
    b -= B_x;
    const int B_lid = (n * 28 + 255) / 256;
    if (b < B_lid) {
        const int idx = b * 256 + tid;
        if (idx < n * 28) {
            const int row = idx / 28;
            const int c = (idx % 28) * 8;
            unsigned short vals[8];
#pragma unroll
            for (int j = 0; j < 8; ++j) {
                const int k = c + j;
                vals[j] = (k < 195) ? f2bf(lid_ts[(size_t)row * 195 + k]) : (unsigned short)0;
            }
            *reinterpret_cast<uint4*>(lidb + (size_t)row * 224 + c) = *reinterpret_cast<uint4*>(vals);
        }
        return;
    }
    b -= B_lid;
    const float* Wsrc;
    unsigned short* Wdst;
    int K, KR, M;
    if (b < 32)        { Wsrc = W1;   Wdst = W1t; K = 64;  KR = 64;  M = 128; }
    else if (b < 144)  { b -= 32;  Wsrc = Wlid; Wdst = Wlt; K = 224; KR = 195; M = 128; }
    else if (b < 272)  { b -= 144; Wsrc = W2;   Wdst = W2t; K = 128; KR = 128; M = 256; }
    else if (b < 400)  { b -= 272; Wsrc = W3;   Wdst = W3t; K = 256; KR = 256; M = 128; }
    else return;
    const int idx = b * 256 + tid;
    if (idx < M * K) {
        const int m = idx / K;
        const int k = idx % K;
        Wdst[idx] = (k < KR) ? f2bf(Wsrc[(size_t)k * M + m]) : (unsigned short)0;
    }
}

// ---------- CSR build ----------
__global__ void scan_block(const unsigned long long* __restrict__ dc, int* __restrict__ incl,
                           int* __restrict__ bsum, int n) {
    __shared__ int sm[256];
    int i = blockIdx.x * 256 + threadIdx.x;
    int v = (i < n) ? (int)(dc[i] >> 40) : 0;
    sm[threadIdx.x] = v;
    __syncthreads();
    for (int off = 1; off < 256; off <<= 1) {
        int t = (threadIdx.x >= off) ? sm[threadIdx.x - off] : 0;
        __syncthreads();
        sm[threadIdx.x] += t;
        __syncthreads();
    }
    if (i < n) incl[i] = sm[threadIdx.x];
    if (threadIdx.x == 255) bsum[blockIdx.x] = sm[255];
}

__global__ void scan_sums(int* __restrict__ bsum, int nb) {
    __shared__ int sm[256];
    int v = (threadIdx.x < nb) ? bsum[threadIdx.x] : 0;
    sm[threadIdx.x] = v;
    __syncthreads();
    for (int off = 1; off < 256; off <<= 1) {
        int t = (threadIdx.x >= off) ? sm[threadIdx.x - off] : 0;
        __syncthreads();
        sm[threadIdx.x] += t;
        __syncthreads();
    }
    if (threadIdx.x < nb) bsum[threadIdx.x] = sm[threadIdx.x];
}

__global__ void make_row(const unsigned long long* __restrict__ dc, const int* __restrict__ incl,
                         const int* __restrict__ bsum, int* __restrict__ row,
                         float* __restrict__ dinv, int n, int E) {
    int i = blockIdx.x * 256 + threadIdx.x;
    if (i < n) {
        int b = i >> 8;
        int base = b > 0 ? bsum[b - 1] : 0;
        const unsigned long long v = dc[i];
        const int c = (int)(v >> 40);
        row[i] = base + incl[i] - c;
        dinv[i] = rsqrtf(1.0f + (float)(v & 0xFFFFFFFFFFULL) * (1.0f / 67108864.0f));
    } else if (i == n) {
        row[n] = E;
    }
}

// ---------- shared MFMA GEMM body ----------
template<int K, int KR, int M, int XMODE, bool OB, bool STATS>
__device__ __forceinline__ void mfma_body(
    int bx, int by,
    const unsigned short* __restrict__ Xb, const unsigned short* __restrict__ Wt,
    const float* __restrict__ bias,
    const float* __restrict__ mr, const float* __restrict__ g, const float* __restrict__ be,
    void* __restrict__ Hv, float* __restrict__ parts, int n,
    unsigned short* A_lds, unsigned short* B_lds)
{
    const int tid = threadIdx.x;
    const int r0 = bx * 64;
    const int c0 = by * 64;
    const int srow = tid >> 2;
    const int skc  = tid & 3;
    const int gr   = r0 + srow;
    const int lane = tid & 63;
    const int wv_  = tid >> 6;
    const int arow = wv_ * 16 + (lane & 15);
    const int koff = (lane >> 4) * 8;

    f32x4 acc[4];
#pragma unroll
    for (int ct = 0; ct < 4; ++ct) acc[ct] = (f32x4){0.f, 0.f, 0.f, 0.f};

    for (int kt = 0; kt < K / 32; ++kt) {
        const int k0 = kt * 32;
        const int kb = k0 + skc * 8;
        unsigned short vals[8];
        if constexpr (XMODE == 0) {
            if (gr < n) {
                *reinterpret_cast<uint4*>(vals) =
                    *reinterpret_cast<const uint4*>(Xb + (size_t)gr * KR + kb);
            } else {
#pragma unroll
                for (int j = 0; j < 8; ++j) vals[j] = 0;
            }
        } else {
            if (gr < n) {
                const uint4 wq = *reinterpret_cast<const uint4*>(Xb + (size_t)gr * K + kb);
                const unsigned ws[4] = {wq.x, wq.y, wq.z, wq.w};
#pragma unroll
                for (int j = 0; j < 4; ++j) {
                    const int c = kb + 2 * j;
                    float a = bf2f_lo(ws[j]);
                    float bq = bf2f_hi(ws[j]);
                    float t0 = (a - mr[c]) * mr[K + c] * g[c] + be[c];
                    float t1 = (bq - mr[c + 1]) * mr[K + c + 1] * g[c + 1] + be[c + 1];
                    vals[2 * j]     = f2bf(t0 > 0.f ? t0 : 0.f);
                    vals[2 * j + 1] = f2bf(t1 > 0.f ? t1 : 0.f);
                }
            } else {
#pragma unroll
                for (int j = 0; j < 8; ++j) vals[j] = 0;
            }
        }
        *reinterpret_cast<uint4*>(&A_lds[srow * 40 + skc * 8]) = *reinterpret_cast<uint4*>(vals);
        *reinterpret_cast<uint4*>(&B_lds[srow * 40 + skc * 8]) =
            *reinterpret_cast<const uint4*>(Wt + (size_t)(c0 + srow) * K + k0 + skc * 8);
        __syncthreads();

        const short8 af = *reinterpret_cast<const short8*>(&A_lds[arow * 40 + koff]);
#pragma unroll
        for (int ct = 0; ct < 4; ++ct) {
            const short8 bf = *reinterpret_cast<const short8*>(&B_lds[(ct * 16 + (lane & 15)) * 40 + koff]);
            acc[ct] = __builtin_amdgcn_mfma_f32_16x16x32_bf16(af, bf, acc[ct], 0, 0, 0);
        }
        __syncthreads();
    }

    const int colb = c0 + (lane & 15);
    const int rowb = r0 + wv_ * 16 + (lane >> 4) * 4;
    float cs[4] = {0.f, 0.f, 0.f, 0.f}, cq[4] = {0.f, 0.f, 0.f, 0.f};
#pragma unroll
    for (int ct = 0; ct < 4; ++ct) {
        const int gcol = colb + ct * 16;
        const float bv = bias ? bias[gcol] : 0.f;
#pragma unroll
        for (int r = 0; r < 4; ++r) {
            const int grow = rowb + r;
            if (grow < n) {
                const float val = acc[ct][r] + bv;
                if constexpr (OB) ((unsigned char*)Hv)[(size_t)grow * M + gcol] = f2e5(val);
                else ((unsigned short*)Hv)[(size_t)grow * M + gcol] = f2bf(val);
                if constexpr (STATS) { cs[ct] += val; cq[ct] += val * val; }
            }
        }
    }

    if constexpr (STATS) {
#pragma unroll
        for (int ct = 0; ct < 4; ++ct) {
            cs[ct] += __shfl_xor(cs[ct], 16);
            cs[ct] += __shfl_xor(cs[ct], 32);
            cq[ct] += __shfl_xor(cq[ct], 16);
            cq[ct] += __shfl_xor(cq[ct], 32);
        }
        float* scr = reinterpret_cast<float*>(A_lds);
        if ((lane & 15) == lane) {
#pragma unroll
            for (int ct = 0; ct < 4; ++ct) {
                scr[(wv_ * 4 + ct) * 16 + lane] = cs[ct];
                scr[256 + (wv_ * 4 + ct) * 16 + lane] = cq[ct];
            }
        }
        __syncthreads();
        if (tid < 64) {
            const int ct = tid >> 4;
            const int col = tid & 15;
            float s = 0.f, q = 0.f;
#pragma unroll
            for (int w2 = 0; w2 < 4; ++w2) {
                s += scr[(w2 * 4 + ct) * 16 + col];
                q += scr[256 + (w2 * 4 + ct) * 16 + col];
            }
            const int gcol = c0 + ct * 16 + col;
            parts[(size_t)bx * (2 * M) + gcol] = s;
            parts[(size_t)bx * (2 * M) + M + gcol] = q;
        }
    }
}

template<int K, int KR, int M, int XMODE, bool OB, bool STATS>
__global__ __launch_bounds__(256) void mfma_gemm(
    const unsigned short* __restrict__ Xb, const unsigned short* __restrict__ Wt,
    const float* __restrict__ bias,
    const float* __restrict__ mr, const float* __restrict__ g, const float* __restrict__ be,
    void* __restrict__ Hv, float* __restrict__ parts, int n)
{
    __shared__ __attribute__((aligned(16))) unsigned short A_lds[64 * 40];
    __shared__ __attribute__((aligned(16))) unsigned short B_lds[64 * 40];
    mfma_body<K, KR, M, XMODE, OB, STATS>(blockIdx.x, blockIdx.y, Xb, Wt, bias, mr, g, be,
                                          Hv, parts, n, A_lds, B_lds);
}

// ---------- fill_csr interleaved with lid GEMM (period 3: 2 fill + 1 gemm) ----------
__global__ __launch_bounds__(256) void fill_lid(
    const int* __restrict__ src, const int* __restrict__ dst,
    const float* __restrict__ ew, const float* __restrict__ dinv,
    const int* __restrict__ row, const unsigned short* __restrict__ slot,
    unsigned* __restrict__ recs, int E,
    const unsigned short* __restrict__ lidb, const unsigned short* __restrict__ Wlt,
    const float* __restrict__ blid, unsigned short* __restrict__ Ch, int n)
{
    __shared__ __attribute__((aligned(16))) unsigned short A_lds[64 * 40];
    __shared__ __attribute__((aligned(16))) unsigned short B_lds[64 * 40];
    const int period = blockIdx.x / 3;
    const int off = blockIdx.x % 3;
    if (off < 2) {
        const int e = (period * 2 + off) * 256 + threadIdx.x;
        if (e < E) {
            const int s = src[e], d = dst[e];
            const float nm = dinv[s] * ew[e] * dinv[d];
            const unsigned q = (unsigned)fminf(nm * 32767.0f + 0.5f, 32767.0f);
            const int p = row[d] + (int)slot[e];
            recs[p] = ((unsigned)s << 15) | q;
        }
        return;
    }
    const int bx = period >> 1;
    const int by = period & 1;
    if (bx >= 782) return;
    mfma_body<224, 224, 128, 0, false, false>(bx, by, lidb, Wlt, blid, nullptr, nullptr, nullptr,
                                              Ch, nullptr, n, A_lds, B_lds);
}

// ---------- row-per-thread GEMM (layer 4: K=128, M=24), bf16 in, fp8 out ----------
template<int K, int M, bool XFORM>
__global__ __launch_bounds__(256) void gemm_rowwise(
    const unsigned short* __restrict__ X, const float* __restrict__ W,
    const float* __restrict__ mr, const float* __restrict__ g,
    const float* __restrict__ be, unsigned char* __restrict__ Hb, int n)
{
    __shared__ float Ws[K * M];
    __shared__ float sc[K], sh[K];
    for (int i = threadIdx.x; i < K * M; i += 256) Ws[i] = W[i];
    if (XFORM) {
        for (int i = threadIdx.x; i < K; i += 256) {
            float s = mr[K + i] * g[i];
            sc[i] = s;
            sh[i] = be[i] - mr[i] * s;
        }
    }
    __syncthreads();

    const int row = blockIdx.x * 256 + threadIdx.x;
    if (row >= n) return;

    float acc[M];
#pragma unroll
    for (int c = 0; c < M; ++c) acc[c] = 0.f;

#pragma unroll 2
    for (int kq = 0; kq < K / 8; ++kq) {
        const uint4 wv = *reinterpret_cast<const uint4*>(X + (size_t)row * K + kq * 8);
        const unsigned ws[4] = {wv.x, wv.y, wv.z, wv.w};
#pragma unroll
        for (int j = 0; j < 4; ++j) {
            const int k = kq * 8 + 2 * j;
            float x0 = bf2f_lo(ws[j]);
            float x1 = bf2f_hi(ws[j]);
            if (XFORM) {
                x0 = x0 * sc[k] + sh[k];       x0 = x0 > 0.f ? x0 : 0.f;
                x1 = x1 * sc[k + 1] + sh[k + 1]; x1 = x1 > 0.f ? x1 : 0.f;
            }
#pragma unroll
            for (int c4 = 0; c4 < M / 4; ++c4) {
                const float4 w0 = *reinterpret_cast<const float4*>(&Ws[k * M + c4 * 4]);
                const float4 w1 = *reinterpret_cast<const float4*>(&Ws[(k + 1) * M + c4 * 4]);
                acc[c4 * 4 + 0] += x0 * w0.x + x1 * w1.x;
                acc[c4 * 4 + 1] += x0 * w0.y + x1 * w1.y;
                acc[c4 * 4 + 2] += x0 * w0.z + x1 * w1.z;
                acc[c4 * 4 + 3] += x0 * w0.w + x1 * w1.w;
            }
        }
    }
#pragma unroll
    for (int q = 0; q < M / 8; ++q) {
        uint2 w;
        w.x = packe4(acc[q * 8 + 0], acc[q * 8 + 1], acc[q * 8 + 2], acc[q * 8 + 3]);
        w.y = packe4(acc[q * 8 + 4], acc[q * 8 + 5], acc[q * 8 + 6], acc[q * 8 + 7]);
        *reinterpret_cast<uint2*>(Hb + (size_t)row * M + q * 8) = w;
    }
}

// ---------- CSR gather (fp8 in, fp32 accum, bf16 out), NO LDS ----------
template<int M>
__global__ __launch_bounds__(256) void gather_e5(
    const unsigned char* __restrict__ h, const int* __restrict__ row,
    const unsigned* __restrict__ recs,
    const float* __restrict__ dinv, const float* __restrict__ bias,
    unsigned short* __restrict__ agg, int n)
{
    constexpr int PF = M / 8;
    const int idx = blockIdx.x * 256 + threadIdx.x;
    const int i = idx / PF;
    if (i >= n) return;
    const int f = (idx % PF) * 8;

    float acc[8];
    {
        const uint2 w = *reinterpret_cast<const uint2*>(h + (size_t)i * M + f);
        dec4(w.x, acc);
        dec4(w.y, acc + 4);
    }
    const float di = dinv[i];
    const float d2 = di * di;
#pragma unroll
    for (int j = 0; j < 8; ++j) acc[j] *= d2;
    if (bias) {
#pragma unroll
        for (int j = 0; j < 8; ++j) acc[j] += bias[f + j];
    }

    const int p0 = row[i], p1 = row[i + 1];
    int p = p0;
    for (; p + 2 <= p1; p += 2) {
        const unsigned r0 = recs[p], r1 = recs[p + 1];
        const int s0 = (int)(r0 >> 15), s1 = (int)(r1 >> 15);
        const float nw0 = (float)(r0 & 0x7FFFu) * (1.0f / 32767.0f);
        const float nw1 = (float)(r1 & 0x7FFFu) * (1.0f / 32767.0f);
        const uint2 a = *reinterpret_cast<const uint2*>(h + (size_t)s0 * M + f);
        const uint2 b = *reinterpret_cast<const uint2*>(h + (size_t)s1 * M + f);
        float tv[4];
        dec4(a.x, tv);
        acc[0] += nw0 * tv[0]; acc[1] += nw0 * tv[1]; acc[2] += nw0 * tv[2]; acc[3] += nw0 * tv[3];
        dec4(a.y, tv);
        acc[4] += nw0 * tv[0]; acc[5] += nw0 * tv[1]; acc[6] += nw0 * tv[2]; acc[7] += nw0 * tv[3];
        dec4(b.x, tv);
        acc[0] += nw1 * tv[0]; acc[1] += nw1 * tv[1]; acc[2] += nw1 * tv[2]; acc[3] += nw1 * tv[3];
        dec4(b.y, tv);
        acc[4] += nw1 * tv[0]; acc[5] += nw1 * tv[1]; acc[6] += nw1 * tv[2]; acc[7] += nw1 * tv[3];
    }
    if (p < p1) {
        const unsigned r0 = recs[p];
        const int s0 = (int)(r0 >> 15);
        const float nw0 = (float)(r0 & 0x7FFFu) * (1.0f / 32767.0f);
        const uint2 a = *reinterpret_cast<const uint2*>(h + (size_t)s0 * M + f);
        float tv[4];
        dec4(a.x, tv);
        acc[0] += nw0 * tv[0]; acc[1] += nw0 * tv[1]; acc[2] += nw0 * tv[2]; acc[3] += nw0 * tv[3];
        dec4(a.y, tv);
        acc[4] += nw0 * tv[0]; acc[5] += nw0 * tv[1]; acc[6] += nw0 * tv[2]; acc[7] += nw0 * tv[3];
    }

    uint4 w;
    w.x = pack2(acc[0], acc[1]);
    w.y = pack2(acc[2], acc[3]);
    w.z = pack2(acc[4], acc[5]);
    w.w = pack2(acc[6], acc[7]);
    *reinterpret_cast<uint4*>(agg + (size_t)i * M + f) = w;
}

// ---------- column stats (bf16 input): per-block partial slots, layout b*(2M) ----------
template<int M>
__global__ __launch_bounds__(256) void col_stats_b(const unsigned short* __restrict__ x,
                                                   float* __restrict__ parts, int n) {
    constexpr int PF = M / 8;
    constexpr int RT = 256 / PF;
    __shared__ float smS[256 * 8];
    __shared__ float smQ[256 * 8];
    const int t = threadIdx.x;
    const int f8 = t % PF;
    const int rg = t / PF;
    const bool active = rg < RT;

    float s[8] = {}, q[8] = {};
    if (active) {
        const int rowsPer = (n + gridDim.x - 1) / gridDim.x;
        const int r0 = blockIdx.x * rowsPer;
        const int r1 = min(r0 + rowsPer, n);
        for (int r = r0 + rg; r < r1; r += RT) {
            const uint4 w = *reinterpret_cast<const uint4*>(x + (size_t)r * M + f8 * 8);
            const unsigned ws[4] = {w.x, w.y, w.z, w.w};
#pragma unroll
            for (int j = 0; j < 4; ++j) {
                const float a = bf2f_lo(ws[j]);
                const float b = bf2f_hi(ws[j]);
                s[2 * j]     += a; q[2 * j]     += a * a;
                s[2 * j + 1] += b; q[2 * j + 1] += b * b;
            }
        }
    }
#pragma unroll
    for (int j = 0; j < 8; ++j) { smS[t * 8 + j] = s[j]; smQ[t * 8 + j] = q[j]; }
    __syncthreads();
    if (rg == 0) {
        for (int o = 1; o < RT; ++o) {
#pragma unroll
            for (int j = 0; j < 8; ++j) {
                s[j] += smS[(o * PF + f8) * 8 + j];
                q[j] += smQ[(o * PF + f8) * 8 + j];
            }
        }
        float* dstp = parts + (size_t)blockIdx.x * (2 * M) + f8 * 8;
#pragma unroll
        for (int j = 0; j < 8; ++j) { dstp[j] = s[j]; dstp[M + j] = q[j]; }
    }
}

// ---------- parallel stats finalize ----------
__global__ __launch_bounds__(256) void finalize_stats(
    const float* __restrict__ parts, float* __restrict__ mr,
    int stride, int nblk, int M, float n) {
    __shared__ float smS[256], smQ[256];
    const int t = threadIdx.x;
    const int col = blockIdx.x * 8 + (t & 7);
    const int rg = t >> 3;
    float s = 0.f, q = 0.f;
    if (col < M) {
        for (int b = rg; b < nblk; b += 32) {
            s += parts[(size_t)b * stride + col];
            q += parts[(size_t)b * stride + M + col];
        }
    }
    smS[t] = s;
    smQ[t] = q;
    __syncthreads();
    if (t < 8 && col < M) {
        for (int o = 1; o < 32; ++o) { s += smS[o * 8 + t]; q += smQ[o * 8 + t]; }
        const float mean = s / n;
        const float var = q / n - mean * mean;
        mr[col] = mean;
        mr[M + col] = rsqrtf(fmaxf(var, 0.f) + EPS);
    }
}

// layer1 epilogue: out_fp8 = mask ? 0 : relu(bn(xagg_bf16)) + relu(lid_bf16)   (M=128)
__global__ void bn_relu_lid_mask_e5(const unsigned short* __restrict__ xagg,
                                    const float* __restrict__ mr,
                                    const float* __restrict__ g, const float* __restrict__ be,
                                    const unsigned short* __restrict__ lid,
                                    const float* __restrict__ x_in,
                                    unsigned char* __restrict__ out, int n) {
    int idx = blockIdx.x * 256 + threadIdx.x;
    if (idx >= n * 16) return;
    const int i = idx >> 4;
    const int f = (idx & 15) * 8;
    const bool mask = x_in[(size_t)i * 64] == 0.f;
    const uint4 xv = *reinterpret_cast<const uint4*>(xagg + (size_t)i * 128 + f);
    const uint4 lv = *reinterpret_cast<const uint4*>(lid + (size_t)i * 128 + f);
    const unsigned xs[4] = {xv.x, xv.y, xv.z, xv.w};
    const unsigned ls[4] = {lv.x, lv.y, lv.z, lv.w};
    float o[8];
#pragma unroll
    for (int j = 0; j < 4; ++j) {
        const int c = f + 2 * j;
        float v0 = bf2f_lo(xs[j]), v1 = bf2f_hi(xs[j]);
        float l0 = bf2f_lo(ls[j]), l1 = bf2f_hi(ls[j]);
        float t0 = (v0 - mr[c]) * mr[128 + c] * g[c] + be[c];
        float t1 = (v1 - mr[c + 1]) * mr[128 + c + 1] * g[c + 1] + be[c + 1];
        t0 = (t0 > 0.f ? t0 : 0.f) + (l0 > 0.f ? l0 : 0.f);
        t1 = (t1 > 0.f ? t1 : 0.f) + (l1 > 0.f ? l1 : 0.f);
        o[2 * j]     = mask ? 0.f : t0;
        o[2 * j + 1] = mask ? 0.f : t1;
    }
    uint2 w;
    w.x = packe4(o[0], o[1], o[2], o[3]);
    w.y = packe4(o[4], o[5], o[6], o[7]);
    *reinterpret_cast<uint2*>(out + (size_t)i * 128 + f) = w;
}

// layer4 stage 1: out = relu(bn(x_bf16)) -> d_out fp32, block partials (no atomics)
template<int M>
__global__ __launch_bounds__(256) void bn_relu_partial_b(
    const unsigned short* __restrict__ x, const float* __restrict__ mr,
    const float* __restrict__ g, const float* __restrict__ be,
    float* __restrict__ out, float* __restrict__ partials, int total8) {
    float acc = 0.f;
    for (int c8 = blockIdx.x * 256 + threadIdx.x; c8 < total8; c8 += gridDim.x * 256) {
        const int base = c8 * 8;
        const uint4 w = *reinterpret_cast<const uint4*>(x + base);
        const unsigned ws[4] = {w.x, w.y, w.z, w.w};
        float o[8];
#pragma unroll
        for (int j = 0; j < 4; ++j) {
            const int f0 = (base + 2 * j) % M;
            const int f1 = (base + 2 * j + 1) % M;
            float v0 = bf2f_lo(ws[j]), v1 = bf2f_hi(ws[j]);
            v0 = (v0 - mr[f0]) * mr[M + f0] * g[f0] + be[f0];
            v1 = (v1 - mr[f1]) * mr[M + f1] * g[f1] + be[f1];
            o[2 * j]     = v0 > 0.f ? v0 : 0.f;
            o[2 * j + 1] = v1 > 0.f ? v1 : 0.f;
            acc += o[2 * j] + o[2 * j + 1];
        }
        *reinterpret_cast<float4*>(out + base)     = make_float4(o[0], o[1], o[2], o[3]);
        *reinterpret_cast<float4*>(out + base + 4) = make_float4(o[4], o[5], o[6], o[7]);
    }
    __shared__ float red[256];
    red[threadIdx.x] = acc;
    __syncthreads();
    for (int s = 128; s > 0; s >>= 1) {
        if (threadIdx.x < s) red[threadIdx.x] += red[threadIdx.x + s];
        __syncthreads();
    }
    if (threadIdx.x == 0) partials[blockIdx.x] = red[0];
}

__global__ void final_sum(const float* __restrict__ partials, int nb, float* __restrict__ sumout) {
    float v = 0.f;
    for (int i = threadIdx.x; i < nb; i += 256) v += partials[i];
    __shared__ float red[256];
    red[threadIdx.x] = v;
    __syncthreads();
    for (int s = 128; s > 0; s >>= 1) {
        if (threadIdx.x < s) red[threadIdx.x] += red[threadIdx.x + s];
        __syncthreads();
    }
    if (threadIdx.x == 0) *sumout = red[0];
}

// ---------------------------------------------------------------
extern "C" void kernel_launch(void* const* d_in, const int* in_sizes, int n_in,
                              void* d_out, int out_size, void* d_ws, size_t ws_size,
                              hipStream_t stream) {
    const float* x_in   = (const float*)d_in[0];
    const int*   eidx   = (const int*)d_in[1];
    const float* ew     = (const float*)d_in[2];
    const float* lid_ts = (const float*)d_in[3];
    const float* W1   = (const float*)d_in[4];
    const float* b1   = (const float*)d_in[5];
    const float* Wlid = (const float*)d_in[6];
    const float* blid = (const float*)d_in[7];
    const float* W2   = (const float*)d_in[8];
    const float* b2   = (const float*)d_in[9];
    const float* W3   = (const float*)d_in[10];
    const float* b3   = (const float*)d_in[11];
    const float* W4   = (const float*)d_in[12];
    const float* b4   = (const float*)d_in[13];
    const float* g1   = (const float*)d_in[14];
    const float* be1  = (const float*)d_in[15];
    const float* g2   = (const float*)d_in[16];
    const float* be2  = (const float*)d_in[17];
    const float* g3   = (const float*)d_in[18];
    const float* be3  = (const float*)d_in[19];
    const float* g4   = (const float*)d_in[20];
    const float* be4  = (const float*)d_in[21];

    const int n = in_sizes[0] / 64;   // 50000
    const int E = in_sizes[2];        // 800000
    const int* src = eidx;
    const int* dst = eidx + E;

    // workspace layout
    float* dinv  = (float*)d_ws;              // NN
    float* parts = dinv + NN;                 // 800000
    float* mr    = parts + 800000;            // 512
    float* partials = mr + 512;               // 512
    unsigned long long* dc = (unsigned long long*)(partials + 512);  // NN ull
    unsigned short* Bh  = (unsigned short*)(dc + NN);    // NN*256 bf16
    unsigned short* Ch  = Bh + (size_t)NN * 256;         // NN*128 bf16
    unsigned short* Gh  = Ch + (size_t)NN * 128;         // NN*128 bf16
    unsigned short* Gb  = Gh + (size_t)NN * 128;         // NN*128 bf16
    unsigned short* lidb = Gb + (size_t)NN * 128;        // NN*224 bf16
    unsigned short* W1t = lidb + (size_t)NN * 224;       // 128*64
    unsigned short* Wlt = W1t + 128 * 64;                // 128*224
    unsigned short* W2t = Wlt + 128 * 224;               // 256*128
    unsigned short* W3t = W2t + 256 * 128;               // 128*256
    unsigned char* x8   = (unsigned char*)(W3t + 128 * 256);  // NN*64 fp8
    unsigned char* Cb8  = x8 + (size_t)NN * 64;          // NN*128 fp8
    unsigned char* Bb8  = Cb8 + (size_t)NN * 128;        // NN*24 fp8
    int* incl    = (int*)((((size_t)(Bb8 + (size_t)NN * 24) + 3) / 4) * 4);  // NN
    int* bsum    = incl + NN;                 // 256
    int* row     = bsum + 256;                // NN+2
    unsigned short* slot = (unsigned short*)(row + NN + 2);  // EE ushort
    unsigned* recs = (unsigned*)(slot + EE);  // EE u32

    float* outx = (float*)d_out;              // n*24
    float* outsum = outx + (size_t)n * 24;    // 1

    hipMemsetAsync(dc, 0, (size_t)NN * sizeof(unsigned long long), stream);

    // ---- interleaved preprocess ----
    const int B_deg = (E + 255) / 256;            // 3125
    const int B_x   = (n * 8 + 255) / 256;        // 1563
    const int B_lid = (n * 28 + 255) / 256;       // 5469
    const int B_w   = 400;
    const int B_other = B_x + B_lid + B_w;
    const int periods = max((B_deg + 4) / 5, (B_other + 10) / 11);
    preprocess<<<periods * 16, 256, 0, stream>>>(
        dst, ew, dc, slot, E, x_in, x8, n, lid_ts, lidb,
        W1, W1t, Wlid, Wlt, W2, W2t, W3, W3t);

    // ---- CSR scan ----
    const int nb = (n + 255) / 256;
    scan_block<<<nb, 256, 0, stream>>>(dc, incl, bsum, n);
    scan_sums<<<1, 256, 0, stream>>>(bsum, nb);
    make_row<<<(n + 1 + 255) / 256, 256, 0, stream>>>(dc, incl, bsum, row, dinv, n, E);

    // ---- fill interleaved with lid GEMM ----
    fill_lid<<<1564 * 3, 256, 0, stream>>>(src, dst, ew, dinv, row, slot, recs, E,
                                           lidb, Wlt, blid, Ch, n);

    const int gm64 = (n + 63) / 64;   // 782

    // ---- layer 1: gather -> MFMA(stats) -> finalize -> epilogue ----
    gather_e5<64><<<((size_t)n * 8 + 255) / 256, 256, 0, stream>>>(x8, row, recs, dinv, nullptr, Gb, n);
    mfma_gemm<64, 64, 128, 0, false, true><<<dim3(gm64, 2), 256, 0, stream>>>(Gb, W1t, b1, nullptr, nullptr, nullptr, Bh, parts, n);
    finalize_stats<<<16, 256, 0, stream>>>(parts, mr, 256, gm64, 128, (float)n);
    bn_relu_lid_mask_e5<<<((size_t)n * 16 + 255) / 256, 256, 0, stream>>>(Bh, mr, g1, be1, Ch, x_in, Cb8, n);

    // ---- layer 2: gather -> MFMA(stats) -> finalize ----
    gather_e5<128><<<((size_t)n * 16 + 255) / 256, 256, 0, stream>>>(Cb8, row, recs, dinv, nullptr, Gb, n);
    mfma_gemm<128, 128, 256, 0, false, true><<<dim3(gm64, 4), 256, 0, stream>>>(Gb, W2t, b2, nullptr, nullptr, nullptr, Bh, parts, n);
    finalize_stats<<<32, 256, 0, stream>>>(parts, mr, 512, gm64, 256, (float)n);

    // ---- layer 3: MFMA(BN2 fused, fp8 out) -> gather -> col_stats -> finalize ----
    mfma_gemm<256, 256, 128, 1, true, false><<<dim3(gm64, 2), 256, 0, stream>>>(Bh, W3t, nullptr, mr, g2, be2, Cb8, nullptr, n);
    gather_e5<128><<<((size_t)n * 16 + 255) / 256, 256, 0, stream>>>(Cb8, row, recs, dinv, b3, Gh, n);
    col_stats_b<128><<<SB, 256, 0, stream>>>(Gh, parts, n);
    finalize_stats<<<16, 256, 0, stream>>>(parts, mr, 256, SB, 128, (float)n);

    // ---- layer 4: rowwise GEMM(BN3 fused, fp8 out) -> gather -> col_stats -> finalize -> epilogue+sum ----
    gemm_rowwise<128, 24, true><<<(n + 255) / 256, 256, 0, stream>>>(Gh, W4, mr, g3, be3, Bb8, n);
    gather_e5<24><<<((size_t)n * 3 + 255) / 256, 256, 0, stream>>>(Bb8, row, recs, dinv, b4, Ch, n);
    col_stats_b<24><<<SB, 256, 0, stream>>>(Ch, parts, n);
    finalize_stats<<<3, 256, 0, stream>>>(parts, mr, 48, SB, 24, (float)n);
    bn_relu_partial_b<24><<<240, 256, 0, stream>>>(Ch, mr, g4, be4, outx, partials, n * 24 / 8);
    final_sum<<<1, 256, 0, stream>>>(partials, 240, outsum);
}